// Round 1
// baseline (506.239 us; speedup 1.0000x reference)
//
#include <hip/hip_runtime.h>

#define BATCH 32
#define CH 3
#define HH 256
#define WW 256
#define KS 29
#define PAD 14
#define HIDDEN 32
#define NT_F 1000.0f

// ---------------- prep: per-batch gaussian kernel + zero loss ----------------
__global__ void prep_kernel(const float* __restrict__ sched,
                            const int* __restrict__ t,
                            float* __restrict__ gk,   // [B][32] (29 used)
                            float* __restrict__ out) {
  int b = threadIdx.x;
  if (b == 32) out[0] = 0.0f;            // zero the scalar loss accumulator
  if (b < BATCH) {
    float sigma = sched[t[b]];
    float inv = 1.0f / sigma;
    float w[KS];
    float s = 0.0f;
#pragma unroll
    for (int i = 0; i < KS; i++) {
      float xg = (float)(i - PAD) * inv;
      w[i] = expf(-0.5f * xg * xg);
      s += w[i];
    }
    float rs = 1.0f / s;
#pragma unroll
    for (int i = 0; i < KS; i++) gk[b * 32 + i] = w[i] * rs;
  }
}

// ---------------- vertical blur (reflect in H) ----------------
// one block = one row (b,c,y); 256 threads = 256 x positions
__global__ __launch_bounds__(256) void vblur_kernel(const float* __restrict__ x,
                                                    const float* __restrict__ gk,
                                                    float* __restrict__ v) {
  int row = blockIdx.x;               // 0 .. B*C*H-1
  int y = row & (HH - 1);
  int bc = row >> 8;
  int b = bc / CH;
  int tx = threadIdx.x;
  const float* kb = gk + b * 32;
  const float* xb = x + (size_t)bc * (HH * WW);
  float sum = 0.0f;
#pragma unroll
  for (int ky = 0; ky < KS; ky++) {
    int yy = y - PAD + ky;
    yy = (yy < 0) ? -yy : yy;
    yy = (yy >= HH) ? (2 * HH - 2 - yy) : yy;
    sum += kb[ky] * xb[yy * WW + tx];
  }
  v[(size_t)bc * (HH * WW) + y * WW + tx] = sum;
}

// ---------------- horizontal blur (reflect in W) ----------------
__global__ __launch_bounds__(256) void hblur_kernel(const float* __restrict__ v,
                                                    const float* __restrict__ gk,
                                                    float* __restrict__ z) {
  __shared__ float sh[WW];
  int row = blockIdx.x;
  int bc = row >> 8;
  int b = bc / CH;
  int tx = threadIdx.x;
  size_t base = (size_t)bc * (HH * WW) + (size_t)(row & (HH - 1)) * WW;
  sh[tx] = v[base + tx];
  __syncthreads();
  const float* kb = gk + b * 32;
  float sum = 0.0f;
#pragma unroll
  for (int ky = 0; ky < KS; ky++) {
    int xx = tx - PAD + ky;
    xx = (xx < 0) ? -xx : xx;
    xx = (xx >= WW) ? (2 * WW - 2 - xx) : xx;
    sum += kb[ky] * sh[xx];
  }
  z[base + tx] = sum;
}

// ---------------- fused conv1+ReLU+conv2+MSE ----------------
// grid: (16,16,B); block 256 = 16x16 output tile
__global__ __launch_bounds__(256) void convloss_kernel(
    const float* __restrict__ x, const float* __restrict__ z,
    const float* __restrict__ W1, const float* __restrict__ b1,
    const float* __restrict__ tw, const float* __restrict__ W2,
    const float* __restrict__ b2, const int* __restrict__ t,
    float* __restrict__ out) {
  __shared__ float zs[3 * 20 * 20];       // z tile with halo 2 (zero-padded)
  __shared__ float w1s[27 * 32];          // [k=ci*9+dy*3+dx][o]  -> float4 friendly
  __shared__ float w2s[32 * 9 * 4];       // [o*9+dy*3+dx][c(4, pad)] -> float4
  __shared__ float tc[32];                // b1[o] + tn*tw[o]
  __shared__ float b2s[4];
  __shared__ float hs[HIDDEN * 18 * 18];  // h tile with halo 1
  __shared__ float wsum[4];

  int bx = blockIdx.x, by = blockIdx.y, b = blockIdx.z;
  int tid = threadIdx.x;
  int x0 = bx * 16, y0 = by * 16;
  const float* zb = z + (size_t)b * 3 * HH * WW;

  // stage z tile (20x20x3), zero outside image (conv SAME zero-pads)
  for (int i = tid; i < 1200; i += 256) {
    int ci = i / 400;
    int r = i - ci * 400;
    int yy = r / 20;
    int xx = r - yy * 20;
    int gy = y0 - 2 + yy, gx = x0 - 2 + xx;
    float val = 0.0f;
    if ((unsigned)gy < (unsigned)HH && (unsigned)gx < (unsigned)WW)
      val = zb[ci * (HH * WW) + gy * WW + gx];
    zs[i] = val;
  }
  // stage W1 transposed: w1s[k*32+o] = W1[o*27+k]
  for (int i = tid; i < 864; i += 256) {
    int k = i >> 5, o = i & 31;
    w1s[i] = W1[o * 27 + k];
  }
  // stage W2 transposed+padded: w2s[(o*9+k3)*4+c] = W2[(c*32+o)*9+k3]
  for (int i = tid; i < 1152; i += 256) {
    int c = i & 3;
    int j = i >> 2;
    int o = j / 9;
    int k3 = j - o * 9;
    w2s[i] = (c < 3) ? W2[(c * 32 + o) * 9 + k3] : 0.0f;
  }
  if (tid < 32) {
    float tn = (float)t[b] * (1.0f / NT_F);
    tc[tid] = b1[tid] + tn * tw[tid];
  }
  if (tid < 4) b2s[tid] = (tid < 3) ? b2[tid] : 0.0f;
  __syncthreads();

  // conv1: compute h on 18x18 halo region, 32 channels; thread does 4 o-chans
  const float4* w14 = (const float4*)w1s;
  for (int idx = tid; idx < 2592; idx += 256) {   // 8 ogroups * 324 pixels
    int og = idx / 324;
    int p = idx - og * 324;
    int py = p / 18;
    int px = p - py * 18;
    int o0 = og * 4;
    float a0 = tc[o0], a1 = tc[o0 + 1], a2 = tc[o0 + 2], a3 = tc[o0 + 3];
#pragma unroll
    for (int ci = 0; ci < 3; ci++) {
#pragma unroll
      for (int dy = 0; dy < 3; dy++) {
        const float* zrow = &zs[ci * 400 + (py + dy) * 20 + px];
#pragma unroll
        for (int dx = 0; dx < 3; dx++) {
          float zv = zrow[dx];
          float4 w = w14[(ci * 9 + dy * 3 + dx) * 8 + og];
          a0 += zv * w.x;
          a1 += zv * w.y;
          a2 += zv * w.z;
          a3 += zv * w.w;
        }
      }
    }
    hs[(o0 + 0) * 324 + p] = fmaxf(a0, 0.0f);
    hs[(o0 + 1) * 324 + p] = fmaxf(a1, 0.0f);
    hs[(o0 + 2) * 324 + p] = fmaxf(a2, 0.0f);
    hs[(o0 + 3) * 324 + p] = fmaxf(a3, 0.0f);
  }
  __syncthreads();

  // conv2 + loss: each thread one output pixel, 3 output channels
  int ty = tid >> 4, tx = tid & 15;
  float c0 = b2s[0], c1 = b2s[1], c2 = b2s[2];
  const float4* w24 = (const float4*)w2s;
  for (int o = 0; o < 32; o++) {
#pragma unroll
    for (int dy = 0; dy < 3; dy++) {
      const float* hrow = &hs[o * 324 + (ty + dy) * 18 + tx];
      float h0 = hrow[0], h1 = hrow[1], h2 = hrow[2];
      float4 wa = w24[(o * 3 + dy) * 3 + 0];
      float4 wb = w24[(o * 3 + dy) * 3 + 1];
      float4 wc = w24[(o * 3 + dy) * 3 + 2];
      c0 += h0 * wa.x + h1 * wb.x + h2 * wc.x;
      c1 += h0 * wa.y + h1 * wb.y + h2 * wc.y;
      c2 += h0 * wa.z + h1 * wb.z + h2 * wc.z;
    }
  }

  int gy = y0 + ty, gx = x0 + tx;
  const float* xb = x + (size_t)b * 3 * HH * WW;
  float d0 = xb[0 * HH * WW + gy * WW + gx] - c0;
  float d1 = xb[1 * HH * WW + gy * WW + gx] - c1;
  float d2 = xb[2 * HH * WW + gy * WW + gx] - c2;
  float s = d0 * d0 + d1 * d1 + d2 * d2;

  // wave (64) reduce then block reduce
#pragma unroll
  for (int off = 32; off > 0; off >>= 1) s += __shfl_down(s, off, 64);
  if ((tid & 63) == 0) wsum[tid >> 6] = s;
  __syncthreads();
  if (tid == 0) {
    float tot = wsum[0] + wsum[1] + wsum[2] + wsum[3];
    atomicAdd(out, tot * (1.0f / 6291456.0f));
  }
}

extern "C" void kernel_launch(void* const* d_in, const int* in_sizes, int n_in,
                              void* d_out, int out_size, void* d_ws, size_t ws_size,
                              hipStream_t stream) {
  const float* x = (const float*)d_in[0];
  const int* t = (const int*)d_in[1];
  const float* W1 = (const float*)d_in[2];
  const float* b1 = (const float*)d_in[3];
  const float* tw = (const float*)d_in[4];
  const float* W2 = (const float*)d_in[5];
  const float* b2 = (const float*)d_in[6];
  const float* sched = (const float*)d_in[7];
  float* out = (float*)d_out;

  // workspace layout
  float* gk = (float*)d_ws;                                  // 32*32 floats
  float* v = (float*)((char*)d_ws + 4096);                   // 25165824 B
  float* zb = (float*)((char*)d_ws + 4096 + 25165824);       // 25165824 B

  prep_kernel<<<1, 64, 0, stream>>>(sched, t, gk, out);
  vblur_kernel<<<BATCH * CH * HH, 256, 0, stream>>>(x, gk, v);
  hblur_kernel<<<BATCH * CH * HH, 256, 0, stream>>>(v, gk, zb);
  dim3 grid(16, 16, BATCH);
  convloss_kernel<<<grid, 256, 0, stream>>>(x, zb, W1, b1, tw, W2, b2, t, out);
}

// Round 2
// 281.457 us; speedup vs baseline: 1.7986x; 1.7986x over previous
//
#include <hip/hip_runtime.h>

#define BATCH 32
#define CH 3
#define HH 256
#define WW 256
#define KS 29
#define PAD 14
#define NT_F 1000.0f

// ws float layout:
//   gk    [32][32]  @ 0
//   w1t   [27][32]  @ 1024   (w1t[k*32+o] = W1[o*27+k])
//   w2t   [32][36]  @ 2048   (w2t[o*36+tap*4+c] = W2[(c*32+o)*9+tap])
//   tcond [32][32]  @ 3328   (b1[o] + (t/NT)*tw[o])
//   z     [32][3][256][256] @ 4608

// ---------------- prep ----------------
__global__ void prep_kernel(const float* __restrict__ sched,
                            const int* __restrict__ t,
                            const float* __restrict__ W1,
                            const float* __restrict__ b1,
                            const float* __restrict__ tw,
                            const float* __restrict__ W2,
                            float* __restrict__ ws, float* __restrict__ out) {
  int tid = threadIdx.x;
  if (tid == 0) out[0] = 0.0f;
  float* gk = ws;
  float* w1t = ws + 1024;
  float* w2t = ws + 2048;
  float* tcond = ws + 3328;
  if (tid < BATCH) {
    float sigma = sched[t[tid]];
    float inv = 1.0f / sigma;
    float w[KS];
    float s = 0.0f;
#pragma unroll
    for (int i = 0; i < KS; i++) {
      float xg = (float)(i - PAD) * inv;
      w[i] = expf(-0.5f * xg * xg);
      s += w[i];
    }
    float rs = 1.0f / s;
#pragma unroll
    for (int i = 0; i < KS; i++) gk[tid * 32 + i] = w[i] * rs;
    gk[tid * 32 + 29] = 0.0f; gk[tid * 32 + 30] = 0.0f; gk[tid * 32 + 31] = 0.0f;
  }
  for (int i = tid; i < 864; i += 256) {       // [k][o]
    int k = i >> 5, o = i & 31;
    w1t[i] = W1[o * 27 + k];
  }
  for (int i = tid; i < 1152; i += 256) {      // [o][tap][c]
    int o = i / 36, r = i - o * 36;
    int tap = r >> 2, c = r & 3;
    w2t[i] = (c < 3) ? W2[(c * 32 + o) * 9 + tap] : 0.0f;
  }
  for (int i = tid; i < 1024; i += 256) {      // [b][o]
    int b = i >> 5, o = i & 31;
    tcond[i] = b1[o] + ((float)t[b] * (1.0f / NT_F)) * tw[o];
  }
}

// ---------------- fused separable blur (reflect) ----------------
// block = (b, c, row-group of 16); 256 threads = 256 columns
__global__ __launch_bounds__(256, 2) void blur_kernel(const float* __restrict__ x,
                                                      const float* __restrict__ ws,
                                                      float* __restrict__ z) {
  __shared__ float xs[44][256];   // rows y0-14 .. y0+29 (reflect-mapped)
  __shared__ float vs[16][256];   // vertically blurred
  int blk = blockIdx.x;           // bc*16 + rg
  int rg = blk & 15;
  int bc = blk >> 4;
  int b = bc / CH;
  int y0 = rg * 16;
  int tid = threadIdx.x;
  const float* xp = x + (size_t)bc * (HH * WW);

  // stage 44 rows, float4 loads, reflect row mapping
  int c4 = (tid & 63) * 4;
  int r0 = tid >> 6;
#pragma unroll
  for (int it = 0; it < 11; ++it) {
    int row = r0 + it * 4;
    int gy = y0 - PAD + row;
    gy = (gy < 0) ? -gy : gy;
    gy = (gy >= HH) ? (2 * HH - 2 - gy) : gy;
    *(float4*)&xs[row][c4] = *(const float4*)&xp[gy * WW + c4];
  }
  __syncthreads();

  const float* kb = ws + b * 32;   // uniform per block -> s_load

  // vertical: thread = column tid, 16 output rows
#pragma unroll 4
  for (int yy = 0; yy < 16; ++yy) {
    float sum = 0.0f;
#pragma unroll
    for (int kk = 0; kk < KS; ++kk) sum += kb[kk] * xs[yy + kk][tid];
    vs[yy][tid] = sum;
  }
  __syncthreads();

  // horizontal with reflect on columns
  size_t zbase = (size_t)bc * (HH * WW) + (size_t)y0 * WW;
  for (int yy = 0; yy < 16; ++yy) {
    float sum = 0.0f;
#pragma unroll
    for (int kk = 0; kk < KS; ++kk) {
      int xx = tid - PAD + kk;
      xx = (xx < 0) ? -xx : xx;
      xx = (xx >= WW) ? (2 * WW - 2 - xx) : xx;
      sum += kb[kk] * vs[yy][xx];
    }
    z[zbase + yy * WW + tid] = sum;
  }
}

// ---------------- fused conv1+ReLU+conv2+MSE ----------------
// grid (16,16,B); block 256 = 16x16 output tile
__global__ __launch_bounds__(256, 6) void convloss_kernel(
    const float* __restrict__ x, const float* __restrict__ ws,
    const float* __restrict__ b2, float* __restrict__ out) {
  __shared__ float zs[3][20][20];   // z tile, halo 2, zero-padded (SAME conv)
  __shared__ float hs[16][324];     // h tile (18x18), 16-och chunk
  __shared__ float wsum[4];

  const float* w1t = ws + 1024;
  const float* w2t = ws + 2048;
  const float* tcond = ws + 3328;
  const float* z = ws + 4608;

  int bx = blockIdx.x, by = blockIdx.y, b = blockIdx.z;
  int tid = threadIdx.x;
  int x0 = bx * 16, y0 = by * 16;
  const float* zb = z + (size_t)b * 3 * HH * WW;

  // stage z tile
  for (int i = tid; i < 1200; i += 256) {
    int ci = i / 400;
    int r = i - ci * 400;
    int yy = r / 20, xx = r - yy * 20;
    int gy = y0 - 2 + yy, gx = x0 - 2 + xx;
    float val = 0.0f;
    if ((unsigned)gy < (unsigned)HH && (unsigned)gx < (unsigned)WW)
      val = zb[ci * (HH * WW) + gy * WW + gx];
    (&zs[0][0][0])[i] = val;
  }

  int lane = tid & 63;
  int og = __builtin_amdgcn_readfirstlane(tid >> 6);   // wave-uniform 0..3

  // per-thread pixel slots (6 x 64 covers 324, clamped duplicates benign)
  int pp[6], pbase[6];
#pragma unroll
  for (int i = 0; i < 6; ++i) {
    int p = lane + 64 * i;
    p = (p > 323) ? 323 : p;
    pp[i] = p;
    int py = p / 18, px = p - py * 18;
    pbase[i] = py * 20 + px;
  }

  int ty = tid >> 4, tx = tid & 15;
  float c0 = b2[0], c1 = b2[1], c2 = b2[2];
  __syncthreads();

  const float* zf = &zs[0][0][0];

  for (int chunk = 0; chunk < 2; ++chunk) {
    // ---- conv1: 16 och of this chunk, thread = 4 och x 6 px ----
    const float4 tcv = *(const float4*)(tcond + b * 32 + chunk * 16 + og * 4);
    float4 acc[6];
#pragma unroll
    for (int i = 0; i < 6; ++i) acc[i] = tcv;
    const float* w1p = w1t + chunk * 16 + og * 4;
#pragma unroll
    for (int k = 0; k < 27; ++k) {
      const int ci = k / 9, dy = (k % 9) / 3, dx = k % 3;
      const int koff = ci * 400 + dy * 20 + dx;
      float4 wv = *(const float4*)(w1p + k * 32);   // uniform -> s_load_dwordx4
#pragma unroll
      for (int i = 0; i < 6; ++i) {
        float zv = zf[pbase[i] + koff];
        acc[i].x += zv * wv.x;
        acc[i].y += zv * wv.y;
        acc[i].z += zv * wv.z;
        acc[i].w += zv * wv.w;
      }
    }
#pragma unroll
    for (int i = 0; i < 6; ++i) {
      hs[og * 4 + 0][pp[i]] = fmaxf(acc[i].x, 0.0f);
      hs[og * 4 + 1][pp[i]] = fmaxf(acc[i].y, 0.0f);
      hs[og * 4 + 2][pp[i]] = fmaxf(acc[i].z, 0.0f);
      hs[og * 4 + 3][pp[i]] = fmaxf(acc[i].w, 0.0f);
    }
    __syncthreads();

    // ---- conv2 partial: thread = 1 px, 3 out-ch, 16 och ----
#pragma unroll 2
    for (int ol = 0; ol < 16; ++ol) {
      const float* wo = w2t + (chunk * 16 + ol) * 36;   // uniform -> s_load
#pragma unroll
      for (int dy = 0; dy < 3; ++dy) {
        const float* hrow = &hs[ol][(ty + dy) * 18 + tx];
        float h0 = hrow[0], h1 = hrow[1], h2 = hrow[2];
        c0 += h0 * wo[(dy * 3 + 0) * 4 + 0] + h1 * wo[(dy * 3 + 1) * 4 + 0] + h2 * wo[(dy * 3 + 2) * 4 + 0];
        c1 += h0 * wo[(dy * 3 + 0) * 4 + 1] + h1 * wo[(dy * 3 + 1) * 4 + 1] + h2 * wo[(dy * 3 + 2) * 4 + 1];
        c2 += h0 * wo[(dy * 3 + 0) * 4 + 2] + h1 * wo[(dy * 3 + 1) * 4 + 2] + h2 * wo[(dy * 3 + 2) * 4 + 2];
      }
    }
    __syncthreads();
  }

  // ---- MSE ----
  int gy = y0 + ty, gx = x0 + tx;
  const float* xb = x + (size_t)b * 3 * HH * WW;
  float d0 = xb[0 * HH * WW + gy * WW + gx] - c0;
  float d1 = xb[1 * HH * WW + gy * WW + gx] - c1;
  float d2 = xb[2 * HH * WW + gy * WW + gx] - c2;
  float s = d0 * d0 + d1 * d1 + d2 * d2;
#pragma unroll
  for (int off = 32; off > 0; off >>= 1) s += __shfl_down(s, off);
  if (lane == 0) wsum[tid >> 6] = s;
  __syncthreads();
  if (tid == 0) {
    float tot = wsum[0] + wsum[1] + wsum[2] + wsum[3];
    atomicAdd(out, tot * (1.0f / 6291456.0f));
  }
}

extern "C" void kernel_launch(void* const* d_in, const int* in_sizes, int n_in,
                              void* d_out, int out_size, void* d_ws, size_t ws_size,
                              hipStream_t stream) {
  const float* x = (const float*)d_in[0];
  const int* t = (const int*)d_in[1];
  const float* W1 = (const float*)d_in[2];
  const float* b1 = (const float*)d_in[3];
  const float* tw = (const float*)d_in[4];
  const float* W2 = (const float*)d_in[5];
  const float* b2 = (const float*)d_in[6];
  const float* sched = (const float*)d_in[7];
  float* out = (float*)d_out;
  float* ws = (float*)d_ws;
  float* z = ws + 4608;

  prep_kernel<<<1, 256, 0, stream>>>(sched, t, W1, b1, tw, W2, ws, out);
  blur_kernel<<<BATCH * CH * 16, 256, 0, stream>>>(x, ws, z);
  dim3 grid(16, 16, BATCH);
  convloss_kernel<<<grid, 256, 0, stream>>>(x, ws, b2, out);
}

// Round 3
// 215.648 us; speedup vs baseline: 2.3475x; 1.3052x over previous
//
#include <hip/hip_runtime.h>

#define BATCH 32
#define CH 3
#define HH 256
#define WW 256
#define KS 29
#define PAD 14
#define NT_F 1000.0f

typedef __attribute__((ext_vector_type(8))) short short8;
typedef __attribute__((ext_vector_type(4))) float f32x4;

__device__ inline unsigned short bf16rne(float f) {
  unsigned u = __float_as_uint(f);
  unsigned r = (u + 0x7FFFu + ((u >> 16) & 1u)) >> 16;
  return (unsigned short)r;
}
__device__ inline float bf16tof(unsigned s) {
  return __uint_as_float(s << 16);
}

// ws float layout:
//   gk    [32][32]            @ 0
//   tcond [32][32]            @ 1024
//   w1b   ushort[32][32]      @ 2048  (w1b[o][k] = bf16(W1[o*27+k]), k>=27 -> 0)
//   w2b   ushort[3][16][32]   @ 2560  (w2b[dy][n=dx*4+oc][och])
//   z     ushort[32][3][256][256] @ 3328  (bf16 blurred)

// ---------------- prep ----------------
__global__ void prep_kernel(const float* __restrict__ sched,
                            const int* __restrict__ t,
                            const float* __restrict__ W1,
                            const float* __restrict__ b1,
                            const float* __restrict__ tw,
                            const float* __restrict__ W2,
                            float* __restrict__ ws, float* __restrict__ out) {
  int tid = threadIdx.x;
  if (tid == 0) out[0] = 0.0f;
  float* gk = ws;
  float* tcond = ws + 1024;
  unsigned short* w1b = (unsigned short*)(ws + 2048);
  unsigned short* w2b = (unsigned short*)(ws + 2560);
  if (tid < BATCH) {
    float sigma = sched[t[tid]];
    float inv = 1.0f / sigma;
    float wv[KS];
    float s = 0.0f;
#pragma unroll
    for (int i = 0; i < KS; i++) {
      float xg = (float)(i - PAD) * inv;
      wv[i] = expf(-0.5f * xg * xg);
      s += wv[i];
    }
    float rs = 1.0f / s;
#pragma unroll
    for (int i = 0; i < KS; i++) gk[tid * 32 + i] = wv[i] * rs;
  }
  for (int i = tid; i < 1024; i += 256) {          // w1b
    int o = i >> 5, k = i & 31;
    w1b[i] = (k < 27) ? bf16rne(W1[o * 27 + k]) : (unsigned short)0;
  }
  for (int i = tid; i < 1536; i += 256) {          // w2b
    int dy = i / 512, r = i & 511;
    int n = r >> 5, och = r & 31;
    int dx = n >> 2, oc = n & 3;
    w2b[i] = (dx < 3 && oc < 3)
                 ? bf16rne(W2[((oc * 32 + och) * 3 + dy) * 3 + dx])
                 : (unsigned short)0;
  }
  for (int i = tid; i < 1024; i += 256) {          // tcond
    int b = i >> 5, o = i & 31;
    tcond[i] = b1[o] + ((float)t[b] * (1.0f / NT_F)) * tw[o];
  }
}

// ---------------- blur: register vertical + b128 horizontal, bf16 out -------
__global__ __launch_bounds__(256) void blur_kernel(const float* __restrict__ x,
                                                   const float* __restrict__ ws,
                                                   unsigned short* __restrict__ z) {
  __shared__ float vsp[16][288];   // padded cols: idx = col + 16, col in [-16, 271]
  int blk = blockIdx.x;
  int rg = blk & 15;
  int bc = blk >> 4;
  int b = bc / CH;
  int y0 = rg * 16;
  int tid = threadIdx.x;
  const float* xp = x + (size_t)bc * (HH * WW);
  const float* kb = ws + b * 32;   // uniform -> s_load

  // vertical blur fully in registers; thread = column tid
  float xv[44];
#pragma unroll
  for (int i = 0; i < 44; i++) {
    int gy = y0 - PAD + i;
    gy = (gy < 0) ? -gy : gy;
    gy = (gy >= HH) ? (2 * HH - 2 - gy) : gy;
    xv[i] = xp[gy * WW + tid];
  }
  float acc[16];
#pragma unroll
  for (int yy = 0; yy < 16; yy++) acc[yy] = 0.0f;
#pragma unroll
  for (int kk = 0; kk < KS; kk++) {
    float kv = kb[kk];
#pragma unroll
    for (int yy = 0; yy < 16; yy++) acc[yy] += kv * xv[yy + kk];
  }
#pragma unroll
  for (int yy = 0; yy < 16; yy++) vsp[yy][tid + 16] = acc[yy];
  __syncthreads();
  {
    int row = tid >> 4, i2 = tid & 15;
    vsp[row][i2] = vsp[row][32 - i2];          // col i2-16  -> reflect 16-i2
    vsp[row][272 + i2] = vsp[row][270 - i2];   // col 256+i2 -> reflect 254-i2
  }
  __syncthreads();

  // horizontal: 4 iters, thread handles (row, 4 cols)
  size_t zb = (size_t)bc * (HH * WW);
#pragma unroll
  for (int it = 0; it < 4; ++it) {
    int unit = tid + 256 * it;
    int row = unit >> 6, cg = unit & 63;
    float w[36];
#pragma unroll
    for (int i = 0; i < 9; i++)
      *(float4*)&w[4 * i] = *(const float4*)&vsp[row][4 * (cg + i)];
    float o0 = 0, o1 = 0, o2 = 0, o3 = 0;
#pragma unroll
    for (int kk = 0; kk < KS; kk++) {
      float kv = kb[kk];
      o0 += kv * w[2 + kk];
      o1 += kv * w[3 + kk];
      o2 += kv * w[4 + kk];
      o3 += kv * w[5 + kk];
    }
    unsigned u0 = (unsigned)bf16rne(o0) | ((unsigned)bf16rne(o1) << 16);
    unsigned u1 = (unsigned)bf16rne(o2) | ((unsigned)bf16rne(o3) << 16);
    *(uint2*)&z[zb + (size_t)(y0 + row) * WW + 4 * cg] = make_uint2(u0, u1);
  }
}

// ---------------- fused conv1+ReLU+conv2+MSE via bf16 MFMA ----------------
// grid (16,16,B); block 256 = 4 waves; 16x16 output tile
__global__ __launch_bounds__(256) void convloss_kernel(
    const float* __restrict__ x, const float* __restrict__ ws,
    const float* __restrict__ b2g, float* __restrict__ out) {
  __shared__ unsigned short zs[1200];        // bf16 z tile [3][20][20]
  __shared__ unsigned short hs[324 * 40];    // h [p][och], row 40 (80B, b128-aligned)
  __shared__ unsigned short Es[3][324 * 12]; // E_dy [p][n=dx*4+oc], row 12 (24B)
  __shared__ float wsum[4];

  const float* tcond = ws + 1024;
  const unsigned short* w1b = (const unsigned short*)(ws + 2048);
  const unsigned short* w2b = (const unsigned short*)(ws + 2560);
  const unsigned short* zg = (const unsigned short*)(ws + 3328);

  int bx = blockIdx.x, by = blockIdx.y, b = blockIdx.z;
  int tid = threadIdx.x;
  int x0 = bx * 16, y0 = by * 16;
  const unsigned short* zbp = zg + (size_t)b * 3 * HH * WW;

  // stage z tile (zero outside image: SAME conv zero-pads)
  for (int i = tid; i < 1200; i += 256) {
    int ci = i / 400;
    int r = i - ci * 400;
    int zy = r / 20, zx = r - zy * 20;
    int gy = y0 - 2 + zy, gx = x0 - 2 + zx;
    unsigned short v = 0;
    if ((unsigned)gy < (unsigned)HH && (unsigned)gx < (unsigned)WW)
      v = zbp[ci * (HH * WW) + gy * WW + gx];
    zs[i] = v;
  }

  int lane = tid & 63;
  int q = lane >> 4;        // quad 0..3
  int col = lane & 15;      // MFMA n / m index
  int wv = tid >> 6;        // wave id 0..3

  // weight fragments: B[k = q*8+j][n = col]
  union U4 { short8 s8; uint4 u4; };
  U4 B1a, B1b, B2[3];
  B1a.u4 = *(const uint4*)(w1b + col * 32 + q * 8);
  B1b.u4 = *(const uint4*)(w1b + (col + 16) * 32 + q * 8);
#pragma unroll
  for (int dy = 0; dy < 3; dy++)
    B2[dy].u4 = *(const uint4*)(w2b + dy * 512 + col * 32 + q * 8);
  float tc0 = tcond[b * 32 + col];
  float tc1 = tcond[b * 32 + 16 + col];

  // conv1 A-frag LDS offsets (ushort units) for this lane's k = q*8+j
  int offs[8];
#pragma unroll
  for (int j = 0; j < 8; j++) {
    int kk = q * 8 + j;
    int ci = kk / 9;
    int rem = kk - ci * 9;
    int dy = rem / 3;
    int dx = rem - dy * 3;
    offs[j] = (kk < 27) ? (ci * 400 + dy * 20 + dx) : 0;
  }

  __syncthreads();

  const f32x4 zero4 = {0.0f, 0.0f, 0.0f, 0.0f};

  // ---- P1: conv1 -> h on 18x18 (21 groups of 16 pixels) ----
  for (int g = wv; g < 21; g += 4) {
    int p = g * 16 + col;
    if (p > 323) p = 323;
    int py = p / 18, px = p - py * 18;
    int zoff = py * 20 + px;
    unsigned short e[8];
#pragma unroll
    for (int j = 0; j < 8; j++) e[j] = zs[zoff + offs[j]];
    U4 A;
    A.u4.x = (unsigned)e[0] | ((unsigned)e[1] << 16);
    A.u4.y = (unsigned)e[2] | ((unsigned)e[3] << 16);
    A.u4.z = (unsigned)e[4] | ((unsigned)e[5] << 16);
    A.u4.w = (unsigned)e[6] | ((unsigned)e[7] << 16);
    f32x4 a0 = __builtin_amdgcn_mfma_f32_16x16x32_bf16(A.s8, B1a.s8, zero4, 0, 0, 0);
    f32x4 a1 = __builtin_amdgcn_mfma_f32_16x16x32_bf16(A.s8, B1b.s8, zero4, 0, 0, 0);
    int prow = g * 16 + q * 4;
#pragma unroll
    for (int r = 0; r < 4; r++) {
      int pw = prow + r;
      if (pw < 324) {
        hs[pw * 40 + col] = bf16rne(fmaxf(a0[r] + tc0, 0.0f));
        hs[pw * 40 + col + 16] = bf16rne(fmaxf(a1[r] + tc1, 0.0f));
      }
    }
  }
  __syncthreads();

  // ---- P2: conv2 partials E_dy[p][n=(dx,oc)] ----
  for (int g = wv; g < 21; g += 4) {
    int p = g * 16 + col;
    if (p > 323) p = 323;
    U4 A;
    A.u4 = *(const uint4*)&hs[p * 40 + q * 8];
    f32x4 e0 = __builtin_amdgcn_mfma_f32_16x16x32_bf16(A.s8, B2[0].s8, zero4, 0, 0, 0);
    f32x4 e1 = __builtin_amdgcn_mfma_f32_16x16x32_bf16(A.s8, B2[1].s8, zero4, 0, 0, 0);
    f32x4 e2 = __builtin_amdgcn_mfma_f32_16x16x32_bf16(A.s8, B2[2].s8, zero4, 0, 0, 0);
    int prow = g * 16 + q * 4;
    if (col < 12) {
#pragma unroll
      for (int r = 0; r < 4; r++) {
        int pw = prow + r;
        if (pw < 324) {
          Es[0][pw * 12 + col] = bf16rne(e0[r]);
          Es[1][pw * 12 + col] = bf16rne(e1[r]);
          Es[2][pw * 12 + col] = bf16rne(e2[r]);
        }
      }
    }
  }
  __syncthreads();

  // ---- P3: 9-point gather + MSE ----
  int ty = tid >> 4, tx = tid & 15;
  float c0 = b2g[0], c1 = b2g[1], c2 = b2g[2];
#pragma unroll
  for (int dy = 0; dy < 3; dy++) {
    const unsigned short* E = &Es[dy][0];
#pragma unroll
    for (int dx = 0; dx < 3; dx++) {
      int pp = (ty + dy) * 18 + tx + dx;
      unsigned uu = *(const unsigned*)&E[pp * 12 + dx * 4];
      c0 += bf16tof(uu & 0xffffu);
      c1 += bf16tof(uu >> 16);
      c2 += bf16tof((unsigned)E[pp * 12 + dx * 4 + 2]);
    }
  }

  int gy = y0 + ty, gx = x0 + tx;
  const float* xb = x + (size_t)b * 3 * HH * WW;
  float d0 = xb[gy * WW + gx] - c0;
  float d1 = xb[HH * WW + gy * WW + gx] - c1;
  float d2 = xb[2 * HH * WW + gy * WW + gx] - c2;
  float s = d0 * d0 + d1 * d1 + d2 * d2;
#pragma unroll
  for (int off = 32; off > 0; off >>= 1) s += __shfl_down(s, off);
  if (lane == 0) wsum[wv] = s;
  __syncthreads();
  if (tid == 0) {
    float tot = wsum[0] + wsum[1] + wsum[2] + wsum[3];
    atomicAdd(out, tot * (1.0f / 6291456.0f));
  }
}

extern "C" void kernel_launch(void* const* d_in, const int* in_sizes, int n_in,
                              void* d_out, int out_size, void* d_ws, size_t ws_size,
                              hipStream_t stream) {
  const float* x = (const float*)d_in[0];
  const int* t = (const int*)d_in[1];
  const float* W1 = (const float*)d_in[2];
  const float* b1 = (const float*)d_in[3];
  const float* tw = (const float*)d_in[4];
  const float* W2 = (const float*)d_in[5];
  const float* b2 = (const float*)d_in[6];
  const float* sched = (const float*)d_in[7];
  float* out = (float*)d_out;
  float* ws = (float*)d_ws;
  unsigned short* z = (unsigned short*)(ws + 3328);

  prep_kernel<<<1, 256, 0, stream>>>(sched, t, W1, b1, tw, W2, ws, out);
  blur_kernel<<<BATCH * CH * 16, 256, 0, stream>>>(x, ws, z);
  dim3 grid(16, 16, BATCH);
  convloss_kernel<<<grid, 256, 0, stream>>>(x, ws, b2, out);
}